// Round 1
// baseline (264.710 us; speedup 1.0000x reference)
//
#include <hip/hip_runtime.h>

// GRU with per-row sequence lengths. B=4096, T=200, I=64, H=128 (I/H hardcoded).
// Output[b] = h after seq_lengths[b] steps from h0=0.
//
// Structure: 256 blocks x 256 threads. Block owns 16 batch rows for ALL t
// (no inter-block comm). 4 waves N-split the 3H=384 gate outputs so each
// wave owns matching (r,z,n) col-slices -> gate math is wave-local.
// Weights live in VGPR B-fragments (f16), loaded once. h|x live in LDS
// (f16, padded stride 200 halves -> conflict-free ds_read_b128 A-frags).
// MFMA: v_mfma_f32_16x16x32_f16, fp32 accumulate. n-gate h-part and x-part
// accumulated separately (tanh(xn + r*hn) needs them split).

#define I_DIM 64
#define H_DIM 128
#define LDSP 200  // LDS row stride in halves: 192 + 8 pad

typedef _Float16 h8 __attribute__((ext_vector_type(8)));
typedef _Float16 h4 __attribute__((ext_vector_type(4)));
typedef float f4 __attribute__((ext_vector_type(4)));

__device__ __forceinline__ float sigmoid_f(float x) {
    return 1.0f / (1.0f + __expf(-x));
}
__device__ __forceinline__ float tanh_f(float x) {
    // tanh(x) = 1 - 2/(exp(2x)+1); saturates correctly at +/-1
    return 1.0f - 2.0f / (__expf(2.0f * x) + 1.0f);
}

__global__ __launch_bounds__(256, 1)
void gru_seq_kernel(const float* __restrict__ input,
                    const int* __restrict__ seq_lengths,
                    const float* __restrict__ W_ih,
                    const float* __restrict__ W_hh,
                    const float* __restrict__ b_ih,
                    const float* __restrict__ b_hh,
                    float* __restrict__ out,
                    int B, int T) {
    __shared__ __align__(16) _Float16 a_lds[16][LDSP];

    const int tid  = threadIdx.x;
    const int lane = tid & 63;
    const int w    = tid >> 6;     // wave 0..3
    const int base = blockIdx.x * 16;

    const int lrow = lane & 15;    // MFMA A-row / C-col lane index
    const int kgrp = lane >> 4;    // 0..3 (k-group for A/B frags; row-group for C)

    // ---- sequence lengths ----
    int Lq[4];
#pragma unroll
    for (int q = 0; q < 4; ++q) {
        int gr = base + kgrp * 4 + q;
        Lq[q] = (gr < B) ? seq_lengths[gr] : 0;
    }
    int Lmax = 0;
    for (int i = 0; i < 16; ++i) {
        int gr = base + i;
        int L = (gr < B) ? seq_lengths[gr] : 0;
        Lmax = max(Lmax, L);
    }
    if (Lmax > T) Lmax = T;

    // ---- biases (C-layout: col = lane&15 -> value depends on col only) ----
    float br[2], bz[2], bnh[2], bnx[2];
#pragma unroll
    for (int tau = 0; tau < 2; ++tau) {
        int c = w * 32 + tau * 16 + lrow;
        br[tau]  = b_ih[c] + b_hh[c];
        bz[tau]  = b_ih[H_DIM + c] + b_hh[H_DIM + c];
        bnh[tau] = b_hh[2 * H_DIM + c];
        bnx[tau] = b_ih[2 * H_DIM + c];
    }

    // ---- B-fragments: Wcat[j][k] with k 0..127 = W_hh row, 128..191 = W_ih row.
    // B[k][n] frag: lane holds Wcat[col][kbase..kbase+7]; col = Ntile + (lane&15),
    // kbase = kt*32 + (lane>>4)*8. 36 frags held in VGPRs across all 200 steps.
    h8 bw[36];
#pragma unroll
    for (int c = 0; c < 6; ++c) {
        const int gate = c >> 1, tau = c & 1;   // gate 0=r,1=z,2=n
        const int j = gate * H_DIM + w * 32 + tau * 16 + lrow;
#pragma unroll
        for (int kt = 0; kt < 6; ++kt) {
            const int kb = kt * 32 + kgrp * 8;
            const float* src = (kt < 4) ? (W_hh + j * H_DIM + kb)
                                        : (W_ih + j * I_DIM + (kb - H_DIM));
            f4 f0 = *(const f4*)(src);
            f4 f1 = *(const f4*)(src + 4);
            h8 v;
            v[0] = (_Float16)f0[0]; v[1] = (_Float16)f0[1];
            v[2] = (_Float16)f0[2]; v[3] = (_Float16)f0[3];
            v[4] = (_Float16)f1[0]; v[5] = (_Float16)f1[1];
            v[6] = (_Float16)f1[2]; v[7] = (_Float16)f1[3];
            bw[c * 6 + kt] = v;
        }
    }

    // ---- init LDS: zero h region (cols 0..127), stage x(0) (cols 128..191) ----
    {
        int idx = tid * 8;                // 2048 halves / 256 threads
        int r = idx >> 7, cc = idx & 127;
        *(h8*)&a_lds[r][cc] = h8{0, 0, 0, 0, 0, 0, 0, 0};
    }
    const int xrow = tid >> 4;            // 0..15
    const int xc4  = (tid & 15) * 4;      // 0,4,..,60
    const float* xbase = input + (size_t)(base + xrow) * T * I_DIM + xc4;
    const bool xrow_ok = (base + xrow) < B;
    if (Lmax > 0 && xrow_ok) {
        f4 xv = *(const f4*)(xbase);
        h4 hv;
        hv[0] = (_Float16)xv[0]; hv[1] = (_Float16)xv[1];
        hv[2] = (_Float16)xv[2]; hv[3] = (_Float16)xv[3];
        *(h4*)&a_lds[xrow][H_DIM + xc4] = hv;
    }
    __syncthreads();

    // fp32 master copies (per-lane positions: row = kgrp*4+q, col = w*32+tau*16+lrow)
    float hreg[2][4]  = {{0.f, 0.f, 0.f, 0.f}, {0.f, 0.f, 0.f, 0.f}};
    float hnreg[2][4] = {{0.f, 0.f, 0.f, 0.f}, {0.f, 0.f, 0.f, 0.f}};

    for (int t = 0; t < Lmax; ++t) {
        // prefetch x(t+1) into regs (written to LDS after the mid barrier)
        f4 xn_v = {0.f, 0.f, 0.f, 0.f};
        const bool pf = (t + 1 < Lmax) && xrow_ok;
        if (pf) xn_v = *(const f4*)(xbase + (size_t)(t + 1) * I_DIM);

        // A-fragments: lane reads a_lds[lane&15][kt*32 + (lane>>4)*8 .. +7]
        h8 af[6];
#pragma unroll
        for (int kt = 0; kt < 6; ++kt)
            af[kt] = *(const h8*)&a_lds[lrow][kt * 32 + kgrp * 8];

        f4 ar[2], az[2], anh_[2], anx_[2];
#pragma unroll
        for (int tau = 0; tau < 2; ++tau) {
            ar[tau]   = f4{br[tau], br[tau], br[tau], br[tau]};
            az[tau]   = f4{bz[tau], bz[tau], bz[tau], bz[tau]};
            anh_[tau] = f4{bnh[tau], bnh[tau], bnh[tau], bnh[tau]};
            anx_[tau] = f4{bnx[tau], bnx[tau], bnx[tau], bnx[tau]};
#pragma unroll
            for (int kt = 0; kt < 6; ++kt)
                ar[tau] = __builtin_amdgcn_mfma_f32_16x16x32_f16(af[kt], bw[(0 + tau) * 6 + kt], ar[tau], 0, 0, 0);
#pragma unroll
            for (int kt = 0; kt < 6; ++kt)
                az[tau] = __builtin_amdgcn_mfma_f32_16x16x32_f16(af[kt], bw[(2 + tau) * 6 + kt], az[tau], 0, 0, 0);
#pragma unroll
            for (int kt = 0; kt < 4; ++kt)   // n-gate h-part (K 0..127)
                anh_[tau] = __builtin_amdgcn_mfma_f32_16x16x32_f16(af[kt], bw[(4 + tau) * 6 + kt], anh_[tau], 0, 0, 0);
#pragma unroll
            for (int kt = 4; kt < 6; ++kt)   // n-gate x-part (K 128..191)
                anx_[tau] = __builtin_amdgcn_mfma_f32_16x16x32_f16(af[kt], bw[(4 + tau) * 6 + kt], anx_[tau], 0, 0, 0);
        }

        // gate math (wave-local; C layout: col=lane&15 group, row=(lane>>4)*4+q)
#pragma unroll
        for (int tau = 0; tau < 2; ++tau) {
#pragma unroll
            for (int q = 0; q < 4; ++q) {
                float r    = sigmoid_f(ar[tau][q]);
                float z    = sigmoid_f(az[tau][q]);
                float n    = tanh_f(anx_[tau][q] + r * anh_[tau][q]);
                float h    = hreg[tau][q];
                float hnew = n + z * (h - n);
                hreg[tau][q] = hnew;
                if (t < Lq[q]) hnreg[tau][q] = hnew;   // capture at t+1 <= L
            }
        }
        __syncthreads();   // all A-frag reads done before overwriting LDS

        // write h(t+1) as f16
#pragma unroll
        for (int tau = 0; tau < 2; ++tau)
#pragma unroll
            for (int q = 0; q < 4; ++q)
                a_lds[kgrp * 4 + q][w * 32 + tau * 16 + lrow] = (_Float16)hreg[tau][q];
        // write x(t+1) as f16
        if (pf) {
            h4 hv;
            hv[0] = (_Float16)xn_v[0]; hv[1] = (_Float16)xn_v[1];
            hv[2] = (_Float16)xn_v[2]; hv[3] = (_Float16)xn_v[3];
            *(h4*)&a_lds[xrow][H_DIM + xc4] = hv;
        }
        __syncthreads();   // writes visible before next iteration's reads
    }

    // ---- store hn ----
#pragma unroll
    for (int tau = 0; tau < 2; ++tau) {
#pragma unroll
        for (int q = 0; q < 4; ++q) {
            int gr  = base + kgrp * 4 + q;
            int col = w * 32 + tau * 16 + lrow;
            if (gr < B) out[(size_t)gr * H_DIM + col] = hnreg[tau][q];
        }
    }
}

extern "C" void kernel_launch(void* const* d_in, const int* in_sizes, int n_in,
                              void* d_out, int out_size, void* d_ws, size_t ws_size,
                              hipStream_t stream) {
    const float* input = (const float*)d_in[0];
    const int*   seq   = (const int*)d_in[1];
    const float* W_ih  = (const float*)d_in[2];
    const float* W_hh  = (const float*)d_in[3];
    const float* b_ih  = (const float*)d_in[4];
    const float* b_hh  = (const float*)d_in[5];
    float* out = (float*)d_out;

    const int B = in_sizes[1];
    const int T = in_sizes[0] / (B * I_DIM);

    const int grid = (B + 15) / 16;
    gru_seq_kernel<<<grid, 256, 0, stream>>>(input, seq, W_ih, W_hh, b_ih, b_hh, out, B, T);
}

// Round 2
// 167.530 us; speedup vs baseline: 1.5801x; 1.5801x over previous
//
#include <hip/hip_runtime.h>

// GRU with per-row sequence lengths. B=4096, T=200, I=64, H=128 (hardcoded).
// Output[b] = h after seq_lengths[b] steps from h0=0.
//
// Round-2 structure: 256 blocks x 512 threads (8 waves = 2/SIMD for latency
// hiding). Block owns 16 batch rows for ALL t. Wave w owns h-cols
// [w*16, w*16+16) of each of the 3 gates -> gate math wave-local, 18 MFMA
// per wave per step. Weights in VGPR B-frags (f16, loaded once). h|x tile
// double-buffered in LDS -> ONE barrier per step. Fast rcp for sigmoid/tanh
// (no IEEE div sequence). fp32 master h in regs; f16 MFMA operands.

#define I_DIM 64
#define H_DIM 128
#define LDSP 200  // LDS row stride in halves: 192 + 8 pad (stride%128B keeps 2-way max)

typedef _Float16 h8 __attribute__((ext_vector_type(8)));
typedef _Float16 h2 __attribute__((ext_vector_type(2)));
typedef float f4 __attribute__((ext_vector_type(4)));
typedef float f2 __attribute__((ext_vector_type(2)));

__device__ __forceinline__ float fast_rcp(float x) {
    return __builtin_amdgcn_rcpf(x);
}
__device__ __forceinline__ float sigmoid_f(float x) {
    return fast_rcp(1.0f + __expf(-x));
}
__device__ __forceinline__ float tanh_f(float x) {
    // tanh(x) = 1 - 2/(exp(2x)+1); saturates correctly at +/-1
    return 1.0f - 2.0f * fast_rcp(__expf(2.0f * x) + 1.0f);
}

__global__ __launch_bounds__(512, 2)
void gru_seq_kernel(const float* __restrict__ input,
                    const int* __restrict__ seq_lengths,
                    const float* __restrict__ W_ih,
                    const float* __restrict__ W_hh,
                    const float* __restrict__ b_ih,
                    const float* __restrict__ b_hh,
                    float* __restrict__ out,
                    int B, int T) {
    // double-buffered A-tile: [buf][row][h(128) | x(64) | pad]
    __shared__ __align__(16) _Float16 a_lds[2][16][LDSP];

    const int tid  = threadIdx.x;
    const int lane = tid & 63;
    const int w    = tid >> 6;     // wave 0..7
    const int base = blockIdx.x * 16;

    const int lrow = lane & 15;    // MFMA A-row index / C-col index
    const int kgrp = lane >> 4;    // 0..3 (k-group for A/B frags; row-group for C)

    // ---- sequence lengths ----
    int Lq[4];
#pragma unroll
    for (int q = 0; q < 4; ++q) {
        int gr = base + kgrp * 4 + q;
        Lq[q] = (gr < B) ? seq_lengths[gr] : 0;
    }
    int Lmax = 0;
    for (int i = 0; i < 16; ++i) {
        int gr = base + i;
        int L = (gr < B) ? seq_lengths[gr] : 0;
        Lmax = max(Lmax, L);
    }
    if (Lmax > T) Lmax = T;

    // ---- biases (C-layout: value depends on col = w*16 + lrow only) ----
    const int c0 = w * 16 + lrow;
    const float br  = b_ih[c0] + b_hh[c0];
    const float bz  = b_ih[H_DIM + c0] + b_hh[H_DIM + c0];
    const float bnh = b_hh[2 * H_DIM + c0];
    const float bnx = b_ih[2 * H_DIM + c0];

    // ---- B-fragments: Wcat[j][k], k 0..127 = W_hh cols, 128..191 = W_ih cols.
    // Frag (gate,kt): lane holds Wcat[j][kb..kb+7], j = gate*128 + w*16 + lrow,
    // kb = kt*32 + kgrp*8. 18 frags (72 VGPR) held across all steps.
    h8 bw[18];
#pragma unroll
    for (int gate = 0; gate < 3; ++gate) {
        const int j = gate * H_DIM + w * 16 + lrow;
#pragma unroll
        for (int kt = 0; kt < 6; ++kt) {
            const int kb = kt * 32 + kgrp * 8;
            const float* src = (kt < 4) ? (W_hh + j * H_DIM + kb)
                                        : (W_ih + j * I_DIM + (kb - H_DIM));
            f4 f0 = *(const f4*)(src);
            f4 f1 = *(const f4*)(src + 4);
            h8 v;
            v[0] = (_Float16)f0[0]; v[1] = (_Float16)f0[1];
            v[2] = (_Float16)f0[2]; v[3] = (_Float16)f0[3];
            v[4] = (_Float16)f1[0]; v[5] = (_Float16)f1[1];
            v[6] = (_Float16)f1[2]; v[7] = (_Float16)f1[3];
            bw[gate * 6 + kt] = v;
        }
    }

    // ---- init buf0: zero h region (cols 0..127), stage x(0) (cols 128..191) ----
    {
        int idx = tid * 4;                // 2048 halves / 512 threads
        int r = idx >> 7, cc = idx & 127;
        *(h2*)&a_lds[0][r][cc]     = h2{0, 0};
        *(h2*)&a_lds[0][r][cc + 2] = h2{0, 0};
    }
    const int xrow = tid >> 5;            // 0..15
    const int xc2  = (tid & 31) * 2;      // 0,2,..,62
    const float* xbase = input + (size_t)(base + xrow) * T * I_DIM + xc2;
    const bool xrow_ok = (base + xrow) < B;
    if (Lmax > 0 && xrow_ok) {
        f2 xv = *(const f2*)(xbase);
        h2 hv; hv[0] = (_Float16)xv[0]; hv[1] = (_Float16)xv[1];
        *(h2*)&a_lds[0][xrow][H_DIM + xc2] = hv;
    }
    __syncthreads();

    // fp32 master copies (lane's C positions: row = kgrp*4+q, col = w*16+lrow)
    float hreg[4]  = {0.f, 0.f, 0.f, 0.f};
    float hnreg[4] = {0.f, 0.f, 0.f, 0.f};

    for (int t = 0; t < Lmax; ++t) {
        const int cur = t & 1, nxt = cur ^ 1;

        // prefetch x(t+1) into regs (LDS-written at end of iter, before barrier)
        f2 xn_v = {0.f, 0.f};
        const bool pf = (t + 1 < Lmax) && xrow_ok;
        if (pf) xn_v = *(const f2*)(xbase + (size_t)(t + 1) * I_DIM);

        // A-fragments: lane reads a_lds[cur][lane&15][kt*32 + (lane>>4)*8 .. +7]
        h8 af[6];
#pragma unroll
        for (int kt = 0; kt < 6; ++kt)
            af[kt] = *(const h8*)&a_lds[cur][lrow][kt * 32 + kgrp * 8];

        f4 ar  = f4{br, br, br, br};
        f4 az  = f4{bz, bz, bz, bz};
        f4 anh = f4{bnh, bnh, bnh, bnh};
        f4 anx = f4{bnx, bnx, bnx, bnx};
#pragma unroll
        for (int kt = 0; kt < 6; ++kt)
            ar = __builtin_amdgcn_mfma_f32_16x16x32_f16(af[kt], bw[0 * 6 + kt], ar, 0, 0, 0);
#pragma unroll
        for (int kt = 0; kt < 6; ++kt)
            az = __builtin_amdgcn_mfma_f32_16x16x32_f16(af[kt], bw[1 * 6 + kt], az, 0, 0, 0);
#pragma unroll
        for (int kt = 0; kt < 4; ++kt)   // n-gate h-part (K 0..127)
            anh = __builtin_amdgcn_mfma_f32_16x16x32_f16(af[kt], bw[2 * 6 + kt], anh, 0, 0, 0);
#pragma unroll
        for (int kt = 4; kt < 6; ++kt)   // n-gate x-part (K 128..191)
            anx = __builtin_amdgcn_mfma_f32_16x16x32_f16(af[kt], bw[2 * 6 + kt], anx, 0, 0, 0);

        // gate math (C layout: col = w*16+lrow, row = kgrp*4+q)
#pragma unroll
        for (int q = 0; q < 4; ++q) {
            float r    = sigmoid_f(ar[q]);
            float z    = sigmoid_f(az[q]);
            float n    = tanh_f(anx[q] + r * anh[q]);
            float h    = hreg[q];
            float hnew = n + z * (h - n);
            hreg[q] = hnew;
            if (t < Lq[q]) hnreg[q] = hnew;   // capture while t+1 <= L
        }

        // write h(t+1) into the other buffer (reads of it happen after barrier)
#pragma unroll
        for (int q = 0; q < 4; ++q)
            a_lds[nxt][kgrp * 4 + q][w * 16 + lrow] = (_Float16)hreg[q];
        // write x(t+1)
        if (pf) {
            h2 hv; hv[0] = (_Float16)xn_v[0]; hv[1] = (_Float16)xn_v[1];
            *(h2*)&a_lds[nxt][xrow][H_DIM + xc2] = hv;
        }
        __syncthreads();   // buf[nxt] fully written before next iter reads it
    }

    // ---- store hn ----
#pragma unroll
    for (int q = 0; q < 4; ++q) {
        int gr = base + kgrp * 4 + q;
        if (gr < B) out[(size_t)gr * H_DIM + w * 16 + lrow] = hnreg[q];
    }
}

extern "C" void kernel_launch(void* const* d_in, const int* in_sizes, int n_in,
                              void* d_out, int out_size, void* d_ws, size_t ws_size,
                              hipStream_t stream) {
    const float* input = (const float*)d_in[0];
    const int*   seq   = (const int*)d_in[1];
    const float* W_ih  = (const float*)d_in[2];
    const float* W_hh  = (const float*)d_in[3];
    const float* b_ih  = (const float*)d_in[4];
    const float* b_hh  = (const float*)d_in[5];
    float* out = (float*)d_out;

    const int B = in_sizes[1];
    const int T = in_sizes[0] / (B * I_DIM);

    const int grid = (B + 15) / 16;
    gru_seq_kernel<<<grid, 512, 0, stream>>>(input, seq, W_ih, W_hh, b_ih, b_hh, out, B, T);
}